// Round 2
// 396.308 us; speedup vs baseline: 1.2025x; 1.2025x over previous
//
#include <hip/hip_runtime.h>
#include <math.h>

// Problem constants (match reference)
constexpr int N   = 1024;
constexpr int D   = 128;
constexpr int S   = 200;
constexpr int D2  = D / 2;            // float2 elements per row
constexpr int ND2 = N * D2;           // per-step noise stride in float2
constexpr int CHAIN_BLOCKS = (N * D2) / 256;   // 256 blocks own the recurrence
constexpr int PF  = 8;                // noise prefetch depth (S % PF == 0)

// clang builtin vector types — required by __builtin_nontemporal_{load,store}
// (HIP_vector_type float2/float4 are classes and are rejected).
typedef float f2 __attribute__((ext_vector_type(2)));
typedef float f4 __attribute__((ext_vector_type(4)));

// Grid = 256 chain blocks + 1024 y/steps writer blocks (one per sample n).
// Chain blocks run the sequential 200-step recurrence (x, out only).
// Writer blocks stream the step-invariant y broadcast + steps ramp with
// float4 stores. Mixing both in one launch keeps all CUs busy (~20 waves/CU
// during overlap vs 4 waves/CU before).
__global__ __launch_bounds__(256, 4) void langevin_kernel(
    const f2* __restrict__ x0,
    const f4* __restrict__ y0,
    const f2* __restrict__ mean,
    const f2* __restrict__ var,
    const float* __restrict__ gammas,
    const f2* __restrict__ noise,   // [S][N][D2]
    f2* __restrict__ x_tot,         // [N][S][D2]
    f4* __restrict__ y_tot,         // [N][S][D/4]
    f2* __restrict__ outp,          // [N][S][D2]
    float* __restrict__ steps)      // [N][S]
{
    if (blockIdx.x >= CHAIN_BLOCKS) {
        // ---------- y / steps writer: one block per sample n ----------
        const int n   = blockIdx.x - CHAIN_BLOCKS;
        const int t   = threadIdx.x;
        const int col = t & 31;         // float4 column 0..31  (32*4 = 128 floats)
        const int r0  = t >> 5;         // row-group 0..7
        const f4  yv  = y0[(size_t)n * 32 + col];
        f4* yq = y_tot + (size_t)n * (S * 32);
        #pragma unroll
        for (int j = 0; j < S / 8; ++j) {
            const int k = r0 + j * 8;   // wave covers 2 rows = 1 KiB contiguous
            __builtin_nontemporal_store(yv, &yq[(size_t)k * 32 + col]);
        }
        if (t < S) steps[(size_t)n * S + t] = (float)t;
        return;
    }

    // ---------- recurrence chains: one thread per (n, d-pair) ----------
    __shared__ float sg[S];
    __shared__ float ss[S];
    for (int i = threadIdx.x; i < S; i += 256) {
        float g = gammas[i];
        sg[i] = g;
        ss[i] = sqrtf(2.0f * g);
    }
    __syncthreads();

    const int idx = blockIdx.x * 256 + threadIdx.x;  // 0 .. N*D2-1
    const int n   = idx >> 6;                        // idx / D2
    const int dp  = idx & 63;                        // idx % D2

    f2 x        = x0[idx];
    const f2 m  = mean[dp];
    const f2 v  = var[dp];
    const float ivx = 1.0f / v.x;
    const float ivy = 1.0f / v.y;

    const f2* zp = noise + idx;                      // + k*ND2 per step
    f2* xq = x_tot + (size_t)n * (S * D2) + dp;      // + k*D2 per step
    f2* oq = outp  + (size_t)n * (S * D2) + dp;

    // 8-deep software pipeline on the noise stream: 8 loads (4 KiB/wave)
    // in flight while the dependent FMA chain + stores run. All indices
    // compile-time constant -> registers, no scratch.
    f2 zb[PF];
    #pragma unroll
    for (int i = 0; i < PF; ++i)
        zb[i] = __builtin_nontemporal_load(&zp[(size_t)i * ND2]);

    #pragma unroll 1
    for (int kb = 0; kb < S; kb += PF) {
        f2 zn[PF];
        if (kb + PF < S) {
            #pragma unroll
            for (int i = 0; i < PF; ++i)
                zn[i] = __builtin_nontemporal_load(&zp[(size_t)(kb + PF + i) * ND2]);
        }
        #pragma unroll
        for (int i = 0; i < PF; ++i) {
            const int k = kb + i;
            const float g = sg[k];
            const float s = ss[k];
            const float gx = g * ivx;
            const float gy = g * ivy;

            // t_old = x - (g/v)*(x-m)
            const float tox = fmaf(-gx, x.x - m.x, x.x);
            const float toy = fmaf(-gy, x.y - m.y, x.y);
            // x_new = t_old + sqrt(2g)*z
            x.x = fmaf(s, zb[i].x, tox);
            x.y = fmaf(s, zb[i].y, toy);
            // t_new = x_new - (g/v)*(x_new-m)
            const float tnx = fmaf(-gx, x.x - m.x, x.x);
            const float tny = fmaf(-gy, x.y - m.y, x.y);

            f2 o;
            o.x = tox - tnx;
            o.y = toy - tny;

            __builtin_nontemporal_store(x, &xq[(size_t)k * D2]);
            __builtin_nontemporal_store(o, &oq[(size_t)k * D2]);
        }
        #pragma unroll
        for (int i = 0; i < PF; ++i) zb[i] = zn[i];
    }
}

extern "C" void kernel_launch(void* const* d_in, const int* in_sizes, int n_in,
                              void* d_out, int out_size, void* d_ws, size_t ws_size,
                              hipStream_t stream)
{
    const float* x0     = (const float*)d_in[0];
    const float* y0     = (const float*)d_in[1];
    const float* mean   = (const float*)d_in[2];
    const float* var    = (const float*)d_in[3];
    const float* gammas = (const float*)d_in[4];
    const float* noise  = (const float*)d_in[5];

    float* x_tot = (float*)d_out;                       // N*S*D
    float* y_tot = x_tot + (size_t)N * S * D;           // N*S*D
    float* outp  = y_tot + (size_t)N * S * D;           // N*S*D
    float* steps = outp  + (size_t)N * S * D;           // N*S

    dim3 grid(CHAIN_BLOCKS + N);   // 256 chain blocks + 1024 y-writer blocks
    dim3 block(256);
    langevin_kernel<<<grid, block, 0, stream>>>(
        (const f2*)x0, (const f4*)y0, (const f2*)mean,
        (const f2*)var, gammas, (const f2*)noise,
        (f2*)x_tot, (f4*)y_tot, (f2*)outp, steps);
}